// Round 9
// baseline (224.646 us; speedup 1.0000x reference)
//
#include <hip/hip_runtime.h>
#include <hip/hip_bf16.h>

#define C 128
#define G 8
#define KNN 16
#define EPS 1e-5f

typedef unsigned short u16;
typedef __attribute__((ext_vector_type(8))) short short8;   // 8 bf16 = 4 VGPRs
typedef __attribute__((ext_vector_type(4))) float float4v;  // MFMA accumulator

union frag_u { short8 v; u16 u[8]; unsigned d[4]; };

__device__ inline u16 f2bf(float f) {
    unsigned u = __builtin_bit_cast(unsigned, f);
    unsigned r = (u + 0x7fffu + ((u >> 16) & 1u)) >> 16;
    return (u16)r;
}
__device__ inline float bf2f(u16 h) {
    unsigned u = ((unsigned)h) << 16;
    return __builtin_bit_cast(float, u);
}
__device__ inline unsigned pkbf(float a, float b) {
    __hip_bfloat162 h = __float22bfloat162_rn(float2{a, b});
    unsigned r;
    __builtin_memcpy(&r, &h, 4);
    return r;
}

// ---------------------------------------------------------------------------
// Prep: swizzle weights into MFMA B-frag bf16 layout.
//  128x128 W -> [cb 8][kk 4][quad 4][lan 16][j 8]; elem = W[kk*32+quad*8+j][cb*16+lan]
//  Ww1 (128x8), Wp2' = Wp2@Ww1 (128x8): single-cb frag (4096), zero lan>=8.
//  Wp1 fold: W''[k][col] = Wp1[k][col]*s(col) (k<3), row k=3 = bp1*s+betap1,
//    s = gp1/sqrt(1+eps). A supplies 1.0 at k=3 -> h1 = relu(MFMA) directly.
//  cw1[g] = bp2 . Ww1[:,g].
// ---------------------------------------------------------------------------
__global__ __launch_bounds__(256) void prep_w(
    const float* __restrict__ Wk, const float* __restrict__ Wv,
    const float* __restrict__ Wq, const float* __restrict__ Wp2,
    const float* __restrict__ Ww1, const float* __restrict__ Wp1,
    const float* __restrict__ bp1, const float* __restrict__ gp1,
    const float* __restrict__ betap1, const float* __restrict__ bp2,
    u16* __restrict__ dst, float* __restrict__ cw1)
{
    const int b = blockIdx.x, t = threadIdx.x;
    if (b < 16) {
        const int mi = b >> 2, qt = b & 3;
        const float* W = mi == 0 ? Wk : mi == 1 ? Wv : mi == 2 ? Wq : Wp2;
        u16* d = dst + mi * 16384;
        for (int e = qt * 4096 + t; e < (qt + 1) * 4096; e += 256) {
            const int k = e >> 7, n = e & 127;
            const int cb = n >> 4, lan = n & 15;
            const int kk = k >> 5, quad = (k >> 3) & 3, j = k & 7;
            d[(((cb * 4 + kk) * 4 + quad) * 16 + lan) * 8 + j] = f2bf(W[e]);
        }
    } else if (b == 16) {
        u16* d = dst + 4 * 16384;
        for (int e = t; e < 4096; e += 256) {
            const int j = e & 7, lan = (e >> 3) & 15;
            const int quad = (e >> 7) & 3, kk = e >> 9;
            const int k = kk * 32 + quad * 8 + j;
            d[e] = lan < 8 ? f2bf(Ww1[k * G + lan]) : (u16)0;
        }
    } else if (b == 17) {
        // Wp2' = Wp2 @ Ww1 -> B-frag; cw1 = bp2 @ Ww1
        u16* d = dst + 4 * 16384 + 4096;
        for (int e = t; e < 4096; e += 256) d[e] = 0;
        __syncthreads();
#pragma unroll
        for (int it = 0; it < 4; it++) {
            const int k = it * 32 + (t >> 3), g = t & 7;
            float a = 0.f;
            for (int i = 0; i < C; i++)
                a = fmaf(Wp2[k * C + i], Ww1[i * G + g], a);
            const int kk = k >> 5, quad = (k >> 3) & 3, j = k & 7;
            d[((kk * 4 + quad) * 16 + g) * 8 + j] = f2bf(a);
        }
        if (t < G) {
            float a = 0.f;
            for (int i = 0; i < C; i++) a = fmaf(bp2[i], Ww1[i * G + t], a);
            cw1[t] = a;
        }
    } else {
        // Wp1 bn-folded, K=32-padded B-frag [cb 8][quad 4][lan 16][j 8]
        u16* d = dst + 4 * 16384 + 2 * 4096;
        for (int e = t; e < 4096; e += 256) d[e] = 0;
        __syncthreads();
        if (t < 128) {
            const int cb = t >> 4, lan = t & 15;
            const int col = cb * 16 + lan;
            const float s = gp1[col] * rsqrtf(1.f + EPS);
#pragma unroll
            for (int j = 0; j < 3; j++)
                d[(cb * 64 + lan) * 8 + j] = f2bf(Wp1[j * C + col] * s);
            d[(cb * 64 + lan) * 8 + 3] = f2bf(bp1[col] * s + betap1[col]);
        }
    }
}

// ---------------------------------------------------------------------------
// Fused projections (unchanged from R6): context -> v + K'; query -> Q'.
// ---------------------------------------------------------------------------
__global__ __launch_bounds__(256) void proj_all(
    const float* __restrict__ Xc, const float* __restrict__ Xq,
    const u16* __restrict__ PWk, const float* __restrict__ bk,
    const float* __restrict__ gk, const float* __restrict__ betak,
    const u16* __restrict__ PWv, const float* __restrict__ bv,
    const u16* __restrict__ PWq, const float* __restrict__ bq,
    const float* __restrict__ gq, const float* __restrict__ betaq,
    const u16* __restrict__ PWw1b,
    u16* __restrict__ vout, u16* __restrict__ Kp, u16* __restrict__ Qp,
    int nkv)
{
    __shared__ __align__(16) u16 Xs[64 * 136];
    const int t = threadIdx.x;
    const int w = t >> 6, l = t & 63;
    const int quad = l >> 4, lan = l & 15;
    const bool isq = (int)blockIdx.x >= nkv;
    const long long row0 = (long long)(isq ? blockIdx.x - nkv : blockIdx.x) * 64;
    const float* X = isq ? Xq : Xc;

    {
        const float4* Xv = (const float4*)(X + row0 * C);
#pragma unroll
        for (int i = 0; i < 8; i++) {
            const int e = t + 256 * i;
            const int r = e >> 5, c4 = e & 31;
            const float4 f = Xv[e];
            uint2 p;
            p.x = pkbf(f.x, f.y);
            p.y = pkbf(f.z, f.w);
            *(uint2*)(&Xs[r * 136 + c4 * 4]) = p;
        }
    }
    __syncthreads();

    if (!isq) {
        unsigned vp[2][4][2];
        {
            short8 Bf[2][4];
#pragma unroll
            for (int ct = 0; ct < 2; ct++) {
                const int cb = w * 2 + ct;
#pragma unroll
                for (int kk = 0; kk < 4; kk++)
                    Bf[ct][kk] = *(const short8*)(PWv + (((cb * 4 + kk) * 4 + quad) * 16 + lan) * 8);
            }
            float4v acc[2][4];
#pragma unroll
            for (int ct = 0; ct < 2; ct++)
#pragma unroll
                for (int rt = 0; rt < 4; rt++) acc[ct][rt] = (float4v)0.f;
#pragma unroll
            for (int rt = 0; rt < 4; rt++)
#pragma unroll
                for (int kk = 0; kk < 4; kk++) {
                    const short8 A = *(const short8*)(&Xs[(rt * 16 + lan) * 136 + kk * 32 + quad * 8]);
#pragma unroll
                    for (int ct = 0; ct < 2; ct++)
                        acc[ct][rt] = __builtin_amdgcn_mfma_f32_16x16x32_bf16(
                            A, Bf[ct][kk], acc[ct][rt], 0, 0, 0);
                }
#pragma unroll
            for (int ct = 0; ct < 2; ct++) {
                const float bb = bv[w * 32 + ct * 16 + lan];
#pragma unroll
                for (int rt = 0; rt < 4; rt++)
#pragma unroll
                    for (int h = 0; h < 2; h++)
                        vp[ct][rt][h] = pkbf(acc[ct][rt][2 * h] + bb, acc[ct][rt][2 * h + 1] + bb);
            }
        }
        float4v acck[2][4];
        {
            short8 Bf[2][4];
#pragma unroll
            for (int ct = 0; ct < 2; ct++) {
                const int cb = w * 2 + ct;
#pragma unroll
                for (int kk = 0; kk < 4; kk++)
                    Bf[ct][kk] = *(const short8*)(PWk + (((cb * 4 + kk) * 4 + quad) * 16 + lan) * 8);
            }
#pragma unroll
            for (int ct = 0; ct < 2; ct++)
#pragma unroll
                for (int rt = 0; rt < 4; rt++) acck[ct][rt] = (float4v)0.f;
#pragma unroll
            for (int rt = 0; rt < 4; rt++)
#pragma unroll
                for (int kk = 0; kk < 4; kk++) {
                    const short8 A = *(const short8*)(&Xs[(rt * 16 + lan) * 136 + kk * 32 + quad * 8]);
#pragma unroll
                    for (int ct = 0; ct < 2; ct++)
                        acck[ct][rt] = __builtin_amdgcn_mfma_f32_16x16x32_bf16(
                            A, Bf[ct][kk], acck[ct][rt], 0, 0, 0);
                }
        }
        __syncthreads();

#pragma unroll
        for (int ct = 0; ct < 2; ct++) {
            const int cg = w * 32 + ct * 16 + lan;
            const float bb = bk[cg];
            const float sc = gk[cg] * rsqrtf(1.f + EPS);
            const float sh = betak[cg];
#pragma unroll
            for (int rt = 0; rt < 4; rt++)
#pragma unroll
                for (int reg = 0; reg < 4; reg++) {
                    float y = (acck[ct][rt][reg] + bb) * sc + sh;
                    y = y > 0.f ? y : 0.f;
                    Xs[(rt * 16 + quad * 4 + reg) * 136 + cg] = f2bf(y);
                }
        }
        __syncthreads();

        {
            short8 Bw[4];
#pragma unroll
            for (int kk = 0; kk < 4; kk++)
                Bw[kk] = *(const short8*)(PWw1b + ((kk * 4 + quad) * 16 + lan) * 8);
            float4v ka = (float4v)0.f;
#pragma unroll
            for (int kk = 0; kk < 4; kk++) {
                const short8 A = *(const short8*)(&Xs[(w * 16 + lan) * 136 + kk * 32 + quad * 8]);
                ka = __builtin_amdgcn_mfma_f32_16x16x32_bf16(A, Bw[kk], ka, 0, 0, 0);
            }
            if (lan < G) {
#pragma unroll
                for (int reg = 0; reg < 4; reg++)
                    Kp[(row0 + w * 16 + quad * 4 + reg) * G + lan] = f2bf(ka[reg]);
            }
        }
        __syncthreads();

#pragma unroll
        for (int ct = 0; ct < 2; ct++) {
            const int cg = w * 32 + ct * 16 + lan;
#pragma unroll
            for (int rt = 0; rt < 4; rt++)
#pragma unroll
                for (int h = 0; h < 2; h++) {
                    Xs[(rt * 16 + quad * 4 + 2 * h) * 136 + cg]     = (u16)(vp[ct][rt][h] & 0xffffu);
                    Xs[(rt * 16 + quad * 4 + 2 * h + 1) * 136 + cg] = (u16)(vp[ct][rt][h] >> 16);
                }
        }
        __syncthreads();
#pragma unroll
        for (int i = 0; i < 4; i++) {
            const int e = t + 256 * i;
            const int r = e >> 4, cc = (e & 15) * 8;
            *(short8*)(vout + (row0 + r) * C + cc) = *(const short8*)(&Xs[r * 136 + cc]);
        }
    } else {
        float4v acc[2][4];
        {
            short8 Bf[2][4];
#pragma unroll
            for (int ct = 0; ct < 2; ct++) {
                const int cb = w * 2 + ct;
#pragma unroll
                for (int kk = 0; kk < 4; kk++)
                    Bf[ct][kk] = *(const short8*)(PWq + (((cb * 4 + kk) * 4 + quad) * 16 + lan) * 8);
            }
#pragma unroll
            for (int ct = 0; ct < 2; ct++)
#pragma unroll
                for (int rt = 0; rt < 4; rt++) acc[ct][rt] = (float4v)0.f;
#pragma unroll
            for (int rt = 0; rt < 4; rt++)
#pragma unroll
                for (int kk = 0; kk < 4; kk++) {
                    const short8 A = *(const short8*)(&Xs[(rt * 16 + lan) * 136 + kk * 32 + quad * 8]);
#pragma unroll
                    for (int ct = 0; ct < 2; ct++)
                        acc[ct][rt] = __builtin_amdgcn_mfma_f32_16x16x32_bf16(
                            A, Bf[ct][kk], acc[ct][rt], 0, 0, 0);
                }
        }
        __syncthreads();
#pragma unroll
        for (int ct = 0; ct < 2; ct++) {
            const int cg = w * 32 + ct * 16 + lan;
            const float bb = bq[cg];
            const float sc = gq[cg] * rsqrtf(1.f + EPS);
            const float sh = betaq[cg];
#pragma unroll
            for (int rt = 0; rt < 4; rt++)
#pragma unroll
                for (int reg = 0; reg < 4; reg++) {
                    float y = (acc[ct][rt][reg] + bb) * sc + sh;
                    y = y > 0.f ? y : 0.f;
                    Xs[(rt * 16 + quad * 4 + reg) * 136 + cg] = f2bf(y);
                }
        }
        __syncthreads();
        {
            short8 Bw[4];
#pragma unroll
            for (int kk = 0; kk < 4; kk++)
                Bw[kk] = *(const short8*)(PWw1b + ((kk * 4 + quad) * 16 + lan) * 8);
            float4v qa = (float4v)0.f;
#pragma unroll
            for (int kk = 0; kk < 4; kk++) {
                const short8 A = *(const short8*)(&Xs[(w * 16 + lan) * 136 + kk * 32 + quad * 8]);
                qa = __builtin_amdgcn_mfma_f32_16x16x32_bf16(A, Bw[kk], qa, 0, 0, 0);
            }
            if (lan < G) {
#pragma unroll
                for (int reg = 0; reg < 4; reg++)
                    Qp[(row0 + w * 16 + quad * 4 + reg) * G + lan] = f2bf(qa[reg]);
            }
        }
    }
}

// ---------------------------------------------------------------------------
// Attention v8: ONE QUERY PER WAVE, zero __syncthreads. All LDS wave-private
// (in-order within a wave); cross-lane via shuffles. 5120 B LDS per wave.
// ---------------------------------------------------------------------------
__global__ __launch_bounds__(256) void attn8(
    const u16* __restrict__ vbuf, const u16* __restrict__ Kp,
    const u16* __restrict__ Qp,
    const float* __restrict__ qcoord, const float* __restrict__ ccoord,
    const u16* __restrict__ PWp1b,
    const u16* __restrict__ PWp2, const float* __restrict__ bp2,
    const u16* __restrict__ PWp2pb, const float* __restrict__ cw1,
    const float* __restrict__ bw1,
    const float* __restrict__ gw1, const float* __restrict__ betaw1,
    const float* __restrict__ Ww2, const float* __restrict__ bw2,
    const int* __restrict__ knn, float* __restrict__ out)
{
    __shared__ __align__(16) unsigned char smem[4 * 5120];
    const int t = threadIdx.x;
    const int w = t >> 6, l = t & 63;
    const int quad = l >> 4, lan = l & 15;
    const int m = blockIdx.x * 4 + w;           // one query per wave

    u16*   h1v = (u16*)(smem + w * 5120);       // 16 x 136 bf16: h1 -> peb -> val
    u16*   kg  = h1v + 16 * 136;                // 16 x 8 bf16 gathered K'
    float* wl  = (float*)(kg + 16 * 8);         // 16 x 8 fp32: hw -> weights

    // ---- neighbor indices (lanes 0-15), broadcast via shuffle ----
    int ii = -1;
    if (l < KNN) ii = knn[m * KNN + l];
    const int myrow = l >> 2;                   // gather row for this lane
    const int idxr = __shfl(ii, myrow);
    const float mfrow = idxr >= 0 ? 1.f : 0.f;
    const size_t r0 = idxr >= 0 ? (size_t)idxr : 0;
    const int c0 = (l & 3) * 32;                // 32 cols per lane

    // ---- issue v gathers early (4 x 16B per lane) ----
    frag_u vg[4];
#pragma unroll
    for (int h = 0; h < 4; h++)
        vg[h].v = *(const short8*)(vbuf + r0 * C + c0 + h * 8);

    // ---- lanes 0-15: pos (kept in regs) + K' gather to LDS ----
    float px = 0.f, py = 0.f, pz = 0.f;
    if (l < KNN) {
        const int i0 = ii >= 0 ? ii : 0;
        const float mf = ii >= 0 ? 1.f : 0.f;
        px = (ccoord[i0 * 3 + 0] - qcoord[m * 3 + 0]) * mf;
        py = (ccoord[i0 * 3 + 1] - qcoord[m * 3 + 1]) * mf;
        pz = (ccoord[i0 * 3 + 2] - qcoord[m * 3 + 2]) * mf;
        *(short8*)(&kg[l * G]) = *(const short8*)(Kp + (size_t)i0 * G);
    }

    // ---- h1 = relu(pos @ Wp1'' + b'') via MFMA (bias folded at k=3) ----
    frag_u A0; A0.v = (short8)0;
    if (quad == 0) {
        A0.u[0] = f2bf(px); A0.u[1] = f2bf(py); A0.u[2] = f2bf(pz);
        A0.u[3] = 0x3F80;   // 1.0 bf16
    }
    float4v h1a[8];
#pragma unroll
    for (int ct = 0; ct < 8; ct++) {
        const short8 Bp = *(const short8*)(PWp1b + ((ct * 4 + quad) * 16 + lan) * 8);
        h1a[ct] = __builtin_amdgcn_mfma_f32_16x16x32_bf16(A0.v, Bp, (float4v)0.f, 0, 0, 0);
    }
    // scatter relu(h1) -> h1v (C-layout positions = row-major [row][col])
#pragma unroll
    for (int ct = 0; ct < 8; ct++)
#pragma unroll
        for (int reg = 0; reg < 4; reg++) {
            const float y = h1a[ct][reg] > 0.f ? h1a[ct][reg] : 0.f;
            h1v[(quad * 4 + reg) * 136 + ct * 16 + lan] = f2bf(y);
        }

    // ---- peb = h1 @ Wp2 (+bp2 later) and PEB' = h1 @ Wp2' ----
    float4v pacc[8];
#pragma unroll
    for (int ct = 0; ct < 8; ct++) pacc[ct] = (float4v)0.f;
    float4v pp = (float4v)0.f;
#pragma unroll
    for (int kk = 0; kk < 4; kk++) {
        const short8 A = *(const short8*)(&h1v[lan * 136 + kk * 32 + quad * 8]);
#pragma unroll
        for (int ct = 0; ct < 8; ct++) {
            const short8 Bf = *(const short8*)(PWp2 + (((ct * 4 + kk) * 4 + quad) * 16 + lan) * 8);
            pacc[ct] = __builtin_amdgcn_mfma_f32_16x16x32_bf16(A, Bf, pacc[ct], 0, 0, 0);
        }
        const short8 Bpp = *(const short8*)(PWp2pb + ((kk * 4 + quad) * 16 + lan) * 8);
        pp = __builtin_amdgcn_mfma_f32_16x16x32_bf16(A, Bpp, pp, 0, 0, 0);
    }

    // ---- scatter peb+bp2 bf16 into h1v (all h1 A-reads are done, in order) ----
#pragma unroll
    for (int ct = 0; ct < 8; ct++) {
        const float bb = bp2[ct * 16 + lan];
#pragma unroll
        for (int reg = 0; reg < 4; reg++)
            h1v[(quad * 4 + reg) * 136 + ct * 16 + lan] = f2bf(pacc[ct][reg] + bb);
    }

    // ---- val = vg*mf + peb (read back own gather cols, in order) ----
#pragma unroll
    for (int h = 0; h < 4; h++) {
        frag_u pe, va;
        pe.v = *(const short8*)(&h1v[myrow * 136 + c0 + h * 8]);
#pragma unroll
        for (int x = 0; x < 4; x++)
            va.d[x] = pkbf(fmaf(bf2f(vg[h].u[2 * x]),     mfrow, bf2f(pe.u[2 * x])),
                           fmaf(bf2f(vg[h].u[2 * x + 1]), mfrow, bf2f(pe.u[2 * x + 1])));
        *(short8*)(&h1v[myrow * 136 + c0 + h * 8]) = va.v;
    }

    // ---- logits: L = K'*mf - Q' + PEB' + cw1 + bw1 -> bn -> relu -> hw ----
    const int g = lan & 7;
    const float qpg  = bf2f(Qp[(size_t)m * G + g]);
    const float cst  = cw1[g] + bw1[g];
    const float sg   = gw1[g] * rsqrtf(1.f + EPS);
    const float shg  = betaw1[g];
    const float mfq0 = __shfl(ii, quad * 4 + 0) >= 0 ? 1.f : 0.f;
    const float mfq1 = __shfl(ii, quad * 4 + 1) >= 0 ? 1.f : 0.f;
    const float mfq2 = __shfl(ii, quad * 4 + 2) >= 0 ? 1.f : 0.f;
    const float mfq3 = __shfl(ii, quad * 4 + 3) >= 0 ? 1.f : 0.f;
    const float mfj[4] = {mfq0, mfq1, mfq2, mfq3};
    if (lan < G) {
#pragma unroll
        for (int reg = 0; reg < 4; reg++) {
            const int row = quad * 4 + reg;
            const float kv = bf2f(kg[row * G + g]);
            const float L = kv * mfj[reg] - qpg + pp[reg] + cst;
            const float y = L * sg + shg;
            wl[row * G + g] = y > 0.f ? y : 0.f;   // hw
        }
    }

    // ---- second layer + softmax over 16 neighbors (cross-quad shuffles) ----
    float w2c[G];
#pragma unroll
    for (int gg = 0; gg < G; gg++) w2c[gg] = Ww2[gg * G + g];
    const float bb2 = bw2[g];
    float lg[4];
#pragma unroll
    for (int reg = 0; reg < 4; reg++) {
        const int row = quad * 4 + reg;
        float a = bb2;
#pragma unroll
        for (int gg = 0; gg < G; gg++) a = fmaf(wl[row * G + gg], w2c[gg], a);
        lg[reg] = a;
    }
    float mx = fmaxf(fmaxf(lg[0], lg[1]), fmaxf(lg[2], lg[3]));
    mx = fmaxf(mx, __shfl_xor(mx, 16));
    mx = fmaxf(mx, __shfl_xor(mx, 32));
    float e[4], s = 0.f;
#pragma unroll
    for (int reg = 0; reg < 4; reg++) { e[reg] = __expf(lg[reg] - mx); s += e[reg]; }
    s += __shfl_xor(s, 16);
    s += __shfl_xor(s, 32);
    const float inv = 1.f / s;
    if (lan < G) {
#pragma unroll
        for (int reg = 0; reg < 4; reg++)
            wl[(quad * 4 + reg) * G + g] = e[reg] * inv * mfj[reg];   // final weights
    }

    // ---- out[c] = sum_j val[j][c] * w[j][c>>4]; lane -> cols 2l, 2l+1 ----
    const int cpa = 2 * l;
    const int gout = l >> 3;
    float a0 = 0.f, a1 = 0.f;
#pragma unroll
    for (int j = 0; j < KNN; j++) {
        const unsigned pv = *(const unsigned*)(&h1v[j * 136 + cpa]);
        const float wj = wl[j * G + gout];
        a0 = fmaf(bf2f((u16)(pv & 0xffffu)), wj, a0);
        a1 = fmaf(bf2f((u16)(pv >> 16)), wj, a1);
    }
    float2 o; o.x = a0; o.y = a1;
    *(float2*)(out + (size_t)m * C + cpa) = o;
}

// ---------------------------------------------------------------------------
extern "C" void kernel_launch(void* const* d_in, const int* in_sizes, int n_in,
                              void* d_out, int out_size, void* d_ws, size_t ws_size,
                              hipStream_t stream)
{
    const float* query_feat    = (const float*)d_in[0];
    const float* context_feat  = (const float*)d_in[1];
    const float* query_coord   = (const float*)d_in[2];
    const float* context_coord = (const float*)d_in[3];
    const float* Wq    = (const float*)d_in[4];
    const float* bq    = (const float*)d_in[5];
    const float* gq    = (const float*)d_in[6];
    const float* betaq = (const float*)d_in[7];
    const float* Wk    = (const float*)d_in[8];
    const float* bk    = (const float*)d_in[9];
    const float* gk    = (const float*)d_in[10];
    const float* betak = (const float*)d_in[11];
    const float* Wv    = (const float*)d_in[12];
    const float* bv    = (const float*)d_in[13];
    const float* Wp1   = (const float*)d_in[14];
    const float* bp1   = (const float*)d_in[15];
    const float* gp1   = (const float*)d_in[16];
    const float* betap1= (const float*)d_in[17];
    const float* Wp2   = (const float*)d_in[18];
    const float* bp2   = (const float*)d_in[19];
    const float* Ww1   = (const float*)d_in[20];
    const float* bw1   = (const float*)d_in[21];
    const float* gw1   = (const float*)d_in[22];
    const float* betaw1= (const float*)d_in[23];
    const float* Ww2   = (const float*)d_in[24];
    const float* bw2   = (const float*)d_in[25];
    const int*   knn   = (const int*)d_in[26];

    const int M = in_sizes[0] / C;   // 16384
    const int N = in_sizes[1] / C;   // 131072

    // workspace: v (N*C bf16) | K' (N*G) | Q' (M*G) | prepped weights | cw1
    u16* vb = (u16*)d_ws;
    u16* Kp = vb + (size_t)N * C;
    u16* Qp = Kp + (size_t)N * G;
    u16* pw = Qp + (size_t)M * G;
    u16* pWk    = pw;
    u16* pWv    = pw + 16384;
    u16* pWq    = pw + 2 * 16384;
    u16* pWp2   = pw + 3 * 16384;
    u16* pWw1b  = pw + 4 * 16384;
    u16* pWp2pb = pw + 4 * 16384 + 4096;
    u16* pWp1b  = pw + 4 * 16384 + 2 * 4096;
    float* cw1  = (float*)(pw + 4 * 16384 + 3 * 4096);

    prep_w<<<19, 256, 0, stream>>>(Wk, Wv, Wq, Wp2, Ww1, Wp1, bp1, gp1, betap1,
                                   bp2, pw, cw1);
    proj_all<<<N / 64 + M / 64, 256, 0, stream>>>(
        context_feat, query_feat,
        pWk, bk, gk, betak, pWv, bv,
        pWq, bq, gq, betaq, pWw1b,
        vb, Kp, Qp, N / 64);
    attn8<<<M / 4, 256, 0, stream>>>(vb, Kp, Qp, query_coord, context_coord,
                                     pWp1b, pWp2, bp2,
                                     pWp2pb, cw1, bw1, gw1, betaw1, Ww2, bw2,
                                     knn, (float*)d_out);
}